// Round 3
// baseline (110.417 us; speedup 1.0000x reference)
//
#include <hip/hip_runtime.h>
#include <hip/hip_bf16.h>
#include <math.h>

typedef __bf16 bf16x8 __attribute__((ext_vector_type(8)));
typedef __bf16 bf16x2 __attribute__((ext_vector_type(2)));
typedef short  s16x2  __attribute__((ext_vector_type(2)));
typedef short  s16x4  __attribute__((ext_vector_type(4)));
typedef float  floatx16 __attribute__((ext_vector_type(16)));

// Workspace layout (bytes):
//   Kq    bf16 [2][8192][16]        offset 0        (512 KB)  scaled by sqrt(log2 e)
//   Vswz  bf16 [2][8192][32]        offset 524288   (1 MB)    32x32x8 B-frag swizzled
//   Opart bf16 [2*8192][16][32]     offset 1572864  (16.8 MB) normalized ratios r_s = O_s/l_s
//   Lpart f32  [2*8192][16]         after Opart     (1 MB)
#define KQ_ELEMS (2 * 8192 * 16)
#define OPART_OFF 1572864
#define SQRT_LOG2E 1.2011224087864498f
#define LSPLIT 4

// ---------------- Kernel A: projections ----------------
// v2: 512-thread blocks (4 waves/SIMD) + 2-way ILP split of each 32-long dot chain.
__global__ __launch_bounds__(512) void proj_kernel(
    const float* __restrict__ in, const float* __restrict__ W1,
    const float* __restrict__ b1, const float* __restrict__ W2,
    const float* __restrict__ b2,
    __hip_bfloat16* __restrict__ Kq, __hip_bfloat16* __restrict__ Vswz)
{
    __shared__ float Xs[32][32];
    __shared__ float W1s[16 * 32];
    __shared__ float W2s[32 * 32];
    const int t = threadIdx.x;
    const int bid = blockIdx.x;       // 0..511
    const int b = bid >> 8;
    const int hw = bid & 255;

    {
        int l = t >> 4, cs = (t & 15) * 2;
        float2 v = *(const float2*)(in + (((size_t)b * 32 + l) * 256 + hw) * 32 + cs);
        *(float2*)&Xs[l][cs] = v;
    }
    if (t < 128) *(float4*)&W1s[t * 4] = *(const float4*)(W1 + t * 4);
    if (t < 256) *(float4*)&W2s[t * 4] = *(const float4*)(W2 + t * 4);
    __syncthreads();

    const int c = t & 31;
    const int g = t >> 5;             // 0..15

    {
        int o = g;                    // 0..15
        float a0 = b1[o], a1 = 0.f;
#pragma unroll
        for (int l = 0; l < 16; ++l) {
            a0 += W1s[o * 32 + l] * Xs[l][c];
            a1 += W1s[o * 32 + 16 + l] * Xs[16 + l][c];
        }
        float acc = a0 + a1;
        int k = c >> 1;
        int i = (c & 1) * 4096 + o * 256 + hw;
        Kq[((size_t)b * 8192 + i) * 16 + k] = __float2bfloat16(acc * SQRT_LOG2E);
    }
#pragma unroll
    for (int oo = 0; oo < 2; ++oo) {
        int o = g * 2 + oo;           // 0..31
        float a0 = b2[o], a1 = 0.f;
#pragma unroll
        for (int l = 0; l < 16; ++l) {
            a0 += W2s[o * 32 + l] * Xs[l][c];
            a1 += W2s[o * 32 + 16 + l] * Xs[16 + l][c];
        }
        float acc = a0 + a1;
        // position j = o*256 + hw, channel c; 32x32x8 B-frag swizzle:
        // flat = jt*1024 + gg*256 + h*128 + c*4 + idx
        int j = o * 256 + hw;
        int jt = j >> 5, rem = j & 31;
        int gg = rem >> 3, hh = (rem >> 2) & 1, idx = rem & 3;
        Vswz[(size_t)b * 262144 + jt * 1024 + gg * 256 + hh * 128 + c * 4 + idx] =
            __float2bfloat16(acc);
    }
}

// ---------------- Kernel B: flash attention, LDS-free, bf16 normalized partials ----------------
// block = 256 thr (4 waves), each wave owns 32 i-rows. grid = 2 * 64 * 16 = 2048.
// v4 (post-mortem of v3): lacc-on-matrix-pipe REVERTED (4-deep serial MFMA chain per
// iter cost more than the VALU adds it saved: 101.7 -> 107.5 us). Diagnosis from v3
// counters: MfmaUtil 34 / VALUBusy 35 / HBM 4.6% / Occupancy 27.7% => latency-bound,
// grid-capped residency (1024 blocks = 4 blk/CU). Fixes:
//   - LSPLIT 3->4: 2048 blocks -> 8 blk/CU available, reg cap (~100 VGPR -> 5 w/SIMD)
//     becomes the binding limit instead of the grid.
//   - explicit SW pipeline depth 1: next tile's K/V fragments loaded before computing
//     the current tile, hiding ~200cy L2 latency under the sc->exp->PV chain.
// NOTE: partials via plain streaming stores, NOT atomics — device-scope fp32 atomic
// RMW pins the kernel at ~44 us; store-based split-partials broke that ceiling.
__global__ __launch_bounds__(256) void flash_kernel(
    const __hip_bfloat16* __restrict__ Kq, const __hip_bfloat16* __restrict__ Vswz,
    __hip_bfloat16* __restrict__ Opart, float* __restrict__ Lpart)
{
    const int t = threadIdx.x;
    const int lane = t & 63;
    const int wv = t >> 6;            // 0..3
    const int m = lane & 31;
    const int h = lane >> 5;          // 0/1

    const int bid = blockIdx.x;
    const int s = bid & ((1 << LSPLIT) - 1);
    const int itile = (bid >> LSPLIT) & 63;
    const int b = bid >> (LSPLIT + 6);
    const int i0 = itile * 128 + wv * 32;
    const int niter = (8192 >> LSPLIT) >> 5;   // 16 tiles of 32 j
    const int jt0 = s * niter;

    const __hip_bfloat16* Kb = Kq + (size_t)b * 8192 * 16;
    const __hip_bfloat16* Vb = Vswz + (size_t)b * 262144 + h * 128 + m * 4;

    // Q B-frag (regs): B[k=8h+idx][n=m] = Kq[i0+m][8h+idx]
    const bf16x8 bq = *(const bf16x8*)(Kb + (size_t)(i0 + m) * 16 + h * 8);

    floatx16 oa = {}, ob = {};
    float2 l01 = {0.f, 0.f}, l23 = {0.f, 0.f};

    // ---- software pipeline: preload tile jt0 ----
    bf16x8 ak = *(const bf16x8*)(Kb + (size_t)(jt0 * 32 + m) * 16 + h * 8);
    s16x4 vf0 = *(const s16x4*)(Vb + (size_t)jt0 * 1024 + 0);
    s16x4 vf1 = *(const s16x4*)(Vb + (size_t)jt0 * 1024 + 256);
    s16x4 vf2 = *(const s16x4*)(Vb + (size_t)jt0 * 1024 + 512);
    s16x4 vf3 = *(const s16x4*)(Vb + (size_t)jt0 * 1024 + 768);

#pragma unroll 2
    for (int it = 0; it < niter; ++it) {
        // rotate current tile into c-regs
        const bf16x8 cak = ak;
        const s16x4 cv0 = vf0, cv1 = vf1, cv2 = vf2, cv3 = vf3;
        // issue next tile's loads NOW; ~600cy of compute below hides them
        if (it + 1 < niter) {
            const int jn = jt0 + it + 1;
            ak  = *(const bf16x8*)(Kb + (size_t)(jn * 32 + m) * 16 + h * 8);
            vf0 = *(const s16x4*)(Vb + (size_t)jn * 1024 + 0);
            vf1 = *(const s16x4*)(Vb + (size_t)jn * 1024 + 256);
            vf2 = *(const s16x4*)(Vb + (size_t)jn * 1024 + 512);
            vf3 = *(const s16x4*)(Vb + (size_t)jn * 1024 + 768);
        }

        // S^T(32j x 32i) = K(A) x Q(B), K=16 exact
        floatx16 sc = __builtin_amdgcn_mfma_f32_32x32x16_bf16(cak, bq, (floatx16){}, 0, 0, 0);

        // P = 2^S ; reg 4g+idx holds j_loc = 8g+4h+idx == 32x32x8 A-layout.
#pragma unroll
        for (int g = 0; g < 4; ++g) {
            float e0 = __builtin_amdgcn_exp2f(sc[4 * g + 0]);
            float e1 = __builtin_amdgcn_exp2f(sc[4 * g + 1]);
            float e2 = __builtin_amdgcn_exp2f(sc[4 * g + 2]);
            float e3 = __builtin_amdgcn_exp2f(sc[4 * g + 3]);
            l01.x += e0; l01.y += e1; l23.x += e2; l23.y += e3;
#if defined(__has_builtin) && __has_builtin(__builtin_amdgcn_cvt_pk_bf16_f32)
            bf16x2 plo = __builtin_amdgcn_cvt_pk_bf16_f32(e0, e1);
            bf16x2 phi = __builtin_amdgcn_cvt_pk_bf16_f32(e2, e3);
#else
            bf16x2 plo = {(__bf16)e0, (__bf16)e1};
            bf16x2 phi = {(__bf16)e2, (__bf16)e3};
#endif
            s16x2 lo = __builtin_bit_cast(s16x2, plo);
            s16x2 hi = __builtin_bit_cast(s16x2, phi);
            s16x4 pb = {lo[0], lo[1], hi[0], hi[1]};
            s16x4 vf = (g == 0) ? cv0 : (g == 1) ? cv1 : (g == 2) ? cv2 : cv3;
            if (g < 2)
                oa = __builtin_amdgcn_mfma_f32_32x32x8bf16_1k(pb, vf, oa, 0, 0, 0);
            else
                ob = __builtin_amdgcn_mfma_f32_32x32x8bf16_1k(pb, vf, ob, 0, 0, 0);
        }
    }

    oa = oa + ob;
    // full split-partial row-sum l_s for row i0+m (this lane's column)
    float l = (l01.x + l01.y) + (l23.x + l23.y);
    l += __shfl_xor(l, 32);
    const float rinv = __builtin_amdgcn_rcpf(l);

    // store normalized ratios r_s = O_s / l_s as bf16 (unit-scale, well-conditioned).
    // reg r -> row i_loc=(r&3)+8*(r>>2)+4h, col c=m ; l for row iloc lives in lane iloc
#pragma unroll
    for (int r = 0; r < 16; ++r) {
        int iloc = (r & 3) + 8 * (r >> 2) + 4 * h;
        float lr = __shfl(rinv, iloc);
        size_t row = (size_t)b * 8192 + i0 + iloc;
        Opart[((row << LSPLIT) | s) * 32 + m] = __float2bfloat16(oa[r] * lr);
    }
    if (h == 0)
        Lpart[(((size_t)b * 8192 + i0 + m) << LSPLIT) | s] = l;
}

// ---------------- Kernel C: weighted combine + epilogue ----------------
// out = (sum_s l_s * r_s) / (sum_s l_s) * gamma + in
// v4: 16 splits (LSPLIT=4); Lpart read as 4x float4.
__global__ __launch_bounds__(256) void combine_kernel(
    const unsigned short* __restrict__ Opart, const float* __restrict__ Lpart,
    const float* __restrict__ in, const float* __restrict__ gamma,
    float* __restrict__ out)
{
    const int gid = blockIdx.x * 256 + threadIdx.x;   // 0..262143
    const int row = gid >> 4;                          // 0..16383
    const int c2 = (gid & 15) * 2;
    const unsigned short* op = Opart + (((size_t)row << LSPLIT)) * 32 + c2;
    const float* lp = Lpart + ((size_t)row << LSPLIT);
    float ls[1 << LSPLIT];
#pragma unroll
    for (int q = 0; q < (1 << LSPLIT) / 4; ++q) {
        float4 lv = *(const float4*)(lp + q * 4);
        ls[q * 4 + 0] = lv.x; ls[q * 4 + 1] = lv.y;
        ls[q * 4 + 2] = lv.z; ls[q * 4 + 3] = lv.w;
    }
    float ax = 0.f, ay = 0.f;
    float lsum = 0.f;
#pragma unroll
    for (int s = 0; s < (1 << LSPLIT); ++s) {
        ushort2 u = *(const ushort2*)(op + s * 32);
        float l = ls[s];
        ax += l * __uint_as_float((unsigned)u.x << 16);
        ay += l * __uint_as_float((unsigned)u.y << 16);
        lsum += l;
    }
    const size_t base = (size_t)row * 32 + c2;
    float2 x = *(const float2*)(in + base);
    const float gl = gamma[0] / lsum;
    float2 r;
    r.x = ax * gl + x.x;
    r.y = ay * gl + x.y;
    *(float2*)(out + base) = r;
}

extern "C" void kernel_launch(void* const* d_in, const int* in_sizes, int n_in,
                              void* d_out, int out_size, void* d_ws, size_t ws_size,
                              hipStream_t stream) {
    const float* in = (const float*)d_in[0];
    const float* W1 = (const float*)d_in[1];
    const float* b1 = (const float*)d_in[2];
    const float* W2 = (const float*)d_in[3];
    const float* b2 = (const float*)d_in[4];
    const float* gamma = (const float*)d_in[5];
    float* out = (float*)d_out;

    __hip_bfloat16* Kq = (__hip_bfloat16*)d_ws;
    __hip_bfloat16* Vswz = Kq + KQ_ELEMS;
    __hip_bfloat16* Opart = (__hip_bfloat16*)((char*)d_ws + OPART_OFF);
    float* Lpart = (float*)(Opart + ((size_t)16384 << LSPLIT) * 32);

    proj_kernel<<<512, 512, 0, stream>>>(in, W1, b1, W2, b2, Kq, Vswz);
    flash_kernel<<<2 * 64 * (1 << LSPLIT), 256, 0, stream>>>(Kq, Vswz, Opart, Lpart);
    combine_kernel<<<1024, 256, 0, stream>>>((const unsigned short*)Opart, Lpart, in, gamma, out);
}

// Round 4
// 107.354 us; speedup vs baseline: 1.0285x; 1.0285x over previous
//
#include <hip/hip_runtime.h>
#include <hip/hip_bf16.h>
#include <math.h>

typedef __bf16 bf16x8 __attribute__((ext_vector_type(8)));
typedef __bf16 bf16x2 __attribute__((ext_vector_type(2)));
typedef short  s16x2  __attribute__((ext_vector_type(2)));
typedef short  s16x4  __attribute__((ext_vector_type(4)));
typedef float  floatx16 __attribute__((ext_vector_type(16)));
typedef unsigned u32x4 __attribute__((ext_vector_type(4)));

// Workspace layout (bytes):
//   Kq    bf16 [2][8192][16]        offset 0        (512 KB)  scaled by sqrt(log2 e)
//   Vswz  bf16 [2][8192][32]        offset 524288   (1 MB)    32x32x16 B-frag swizzled
//   Opart bf16 [2*8192][8][32]      offset 1572864  (8.4 MB)  normalized ratios r_s = O_s/l_s
//   Lpart f32  [2*8192][8]          after Opart     (512 KB)
#define KQ_ELEMS (2 * 8192 * 16)
#define OPART_OFF 1572864
#define SQRT_LOG2E 1.2011224087864498f
#define LSPLIT 3

// ---------------- Kernel A: projections ----------------
// v5: Vswz layout changed to the 32x32x16 B-fragment order:
//   V[j][c] at flat = jt*1024 + g'*512 + hh*256 + c*8 + idx,
//   where jl=j&31, g'=jl>>4, hh=(jl>>3)&1, idx=jl&7.
// Each flash lane then loads its 8 k-elems as one contiguous 16B read.
__global__ __launch_bounds__(512) void proj_kernel(
    const float* __restrict__ in, const float* __restrict__ W1,
    const float* __restrict__ b1, const float* __restrict__ W2,
    const float* __restrict__ b2,
    __hip_bfloat16* __restrict__ Kq, __hip_bfloat16* __restrict__ Vswz)
{
    __shared__ float Xs[32][32];
    __shared__ float W1s[16 * 32];
    __shared__ float W2s[32 * 32];
    const int t = threadIdx.x;
    const int bid = blockIdx.x;       // 0..511
    const int b = bid >> 8;
    const int hw = bid & 255;

    {
        int l = t >> 4, cs = (t & 15) * 2;
        float2 v = *(const float2*)(in + (((size_t)b * 32 + l) * 256 + hw) * 32 + cs);
        *(float2*)&Xs[l][cs] = v;
    }
    if (t < 128) *(float4*)&W1s[t * 4] = *(const float4*)(W1 + t * 4);
    if (t < 256) *(float4*)&W2s[t * 4] = *(const float4*)(W2 + t * 4);
    __syncthreads();

    const int c = t & 31;
    const int g = t >> 5;             // 0..15

    {
        int o = g;                    // 0..15
        float a0 = b1[o], a1 = 0.f;
#pragma unroll
        for (int l = 0; l < 16; ++l) {
            a0 += W1s[o * 32 + l] * Xs[l][c];
            a1 += W1s[o * 32 + 16 + l] * Xs[16 + l][c];
        }
        float acc = a0 + a1;
        int k = c >> 1;
        int i = (c & 1) * 4096 + o * 256 + hw;
        Kq[((size_t)b * 8192 + i) * 16 + k] = __float2bfloat16(acc * SQRT_LOG2E);
    }
#pragma unroll
    for (int oo = 0; oo < 2; ++oo) {
        int o = g * 2 + oo;           // 0..31
        float a0 = b2[o], a1 = 0.f;
#pragma unroll
        for (int l = 0; l < 16; ++l) {
            a0 += W2s[o * 32 + l] * Xs[l][c];
            a1 += W2s[o * 32 + 16 + l] * Xs[16 + l][c];
        }
        float acc = a0 + a1;
        // position j = o*256 + hw, channel c; x16 B-frag swizzle:
        int jt = o * 8 + (hw >> 5);
        int gp = (hw >> 4) & 1, hh = (hw >> 3) & 1, idx = hw & 7;
        Vswz[(size_t)b * 262144 + jt * 1024 + gp * 512 + hh * 256 + c * 8 + idx] =
            __float2bfloat16(acc);
    }
}

// ---------------- Kernel B: flash attention, LDS-free, bf16 normalized partials ----------------
// block = 256 thr (4 waves), each wave owns 32 i-rows. grid = 2 * 64 * 8 = 1024.
// v5 (post-mortem of v3/v4): occupancy/prefetch theories didn't move flash (stuck
// ~41us across all variants). R2 PMC arithmetic: MfmaUtil 34.4% over 41.2us =
// ~52 cyc per MFMA avg -> the 4x per-iter legacy mfma_f32_32x32x8bf16_1k PV ops
// run ~quarter-rate on gfx950. Fix: 2x native 32x32x16_bf16 PV MFMAs instead.
// P regroup for the x16 A-layout (lane h needs j=8h+idx, owns j=8g+4h+idx):
// half-wave exchange via __shfl_xor(.,32) + select (safe form; permlane32_swap
// later once the win is confirmed).
// NOTE: partials via plain streaming stores, NOT atomics (atomic RMW pinned ~44us).
__global__ __launch_bounds__(256) void flash_kernel(
    const __hip_bfloat16* __restrict__ Kq, const __hip_bfloat16* __restrict__ Vswz,
    __hip_bfloat16* __restrict__ Opart, float* __restrict__ Lpart)
{
    const int t = threadIdx.x;
    const int lane = t & 63;
    const int wv = t >> 6;            // 0..3
    const int m = lane & 31;
    const int h = lane >> 5;          // 0/1
    const bool hi = (h != 0);

    const int bid = blockIdx.x;
    const int s = bid & ((1 << LSPLIT) - 1);
    const int itile = (bid >> LSPLIT) & 63;
    const int b = bid >> (LSPLIT + 6);
    const int i0 = itile * 128 + wv * 32;
    const int niter = (8192 >> LSPLIT) >> 5;   // 32 tiles of 32 j
    const int jt0 = s * niter;

    const __hip_bfloat16* Kb = Kq + (size_t)b * 8192 * 16;
    const __hip_bfloat16* Vb = Vswz + (size_t)b * 262144 + h * 256 + m * 8;

    // Q B-frag (regs): B[k=8h+idx][n=m] = Kq[i0+m][8h+idx]
    const bf16x8 bq = *(const bf16x8*)(Kb + (size_t)(i0 + m) * 16 + h * 8);

    floatx16 oa = {}, ob = {};
    float2 l01 = {0.f, 0.f}, l23 = {0.f, 0.f};

    // ---- software pipeline: preload tile jt0 ----
    bf16x8 ak = *(const bf16x8*)(Kb + (size_t)(jt0 * 32 + m) * 16 + h * 8);
    bf16x8 vb0 = *(const bf16x8*)(Vb + (size_t)jt0 * 1024 + 0);
    bf16x8 vb1 = *(const bf16x8*)(Vb + (size_t)jt0 * 1024 + 512);

#pragma unroll 2
    for (int it = 0; it < niter; ++it) {
        const bf16x8 cak = ak;
        const bf16x8 cv0 = vb0, cv1 = vb1;
        if (it + 1 < niter) {
            const int jn = jt0 + it + 1;
            ak  = *(const bf16x8*)(Kb + (size_t)(jn * 32 + m) * 16 + h * 8);
            vb0 = *(const bf16x8*)(Vb + (size_t)jn * 1024 + 0);
            vb1 = *(const bf16x8*)(Vb + (size_t)jn * 1024 + 512);
        }

        // S^T(32j x 32i) = K(A) x Q(B), K=16 exact
        floatx16 sc = __builtin_amdgcn_mfma_f32_32x32x16_bf16(cak, bq, (floatx16){}, 0, 0, 0);

        // P = 2^S ; sc reg 4g+idx holds j_loc = 8g+4h+idx, i = m.
        float e[16];
#pragma unroll
        for (int r = 0; r < 16; ++r) e[r] = __builtin_amdgcn_exp2f(sc[r]);
#pragma unroll
        for (int g = 0; g < 4; ++g) {
            l01.x += e[4 * g + 0]; l01.y += e[4 * g + 1];
            l23.x += e[4 * g + 2]; l23.y += e[4 * g + 3];
        }

        // pack pairs: c[g][p] = bf16(e[4g+2p], e[4g+2p+1]) -> (j = 8g+4h+2p, +1)
        unsigned cp[4][2];
#pragma unroll
        for (int g = 0; g < 4; ++g) {
#pragma unroll
            for (int p = 0; p < 2; ++p) {
#if defined(__has_builtin) && __has_builtin(__builtin_amdgcn_cvt_pk_bf16_f32)
                bf16x2 pk = __builtin_amdgcn_cvt_pk_bf16_f32(e[4 * g + 2 * p], e[4 * g + 2 * p + 1]);
#else
                bf16x2 pk = {(__bf16)e[4 * g + 2 * p], (__bf16)e[4 * g + 2 * p + 1]};
#endif
                cp[g][p] = __builtin_bit_cast(unsigned, pk);
            }
        }

        // Regroup to x16 A-layout: lane (m,h) elem idx must hold P[i=m][j=8h+idx].
        // A-frag#0 (j 0..15) from g0,g1; A-frag#1 (j 16..31) from g2,g3.
        // dw0 = h? partner(c[1][0]) : c[0][0]   dw2 = h? c[1][0] : partner(c[0][0])  etc.
        unsigned x00 = __shfl_xor((int)cp[0][0], 32), x01 = __shfl_xor((int)cp[0][1], 32);
        unsigned x10 = __shfl_xor((int)cp[1][0], 32), x11 = __shfl_xor((int)cp[1][1], 32);
        unsigned x20 = __shfl_xor((int)cp[2][0], 32), x21 = __shfl_xor((int)cp[2][1], 32);
        unsigned x30 = __shfl_xor((int)cp[3][0], 32), x31 = __shfl_xor((int)cp[3][1], 32);
        u32x4 pa0u = { hi ? x10 : cp[0][0], hi ? x11 : cp[0][1],
                       hi ? cp[1][0] : x00, hi ? cp[1][1] : x01 };
        u32x4 pa1u = { hi ? x30 : cp[2][0], hi ? x31 : cp[2][1],
                       hi ? cp[3][0] : x20, hi ? cp[3][1] : x21 };
        bf16x8 pa0 = __builtin_bit_cast(bf16x8, pa0u);
        bf16x8 pa1 = __builtin_bit_cast(bf16x8, pa1u);

        // O[i=m][c] += P * V, two native K=16 MFMAs (j 0..15 -> oa, j 16..31 -> ob)
        oa = __builtin_amdgcn_mfma_f32_32x32x16_bf16(pa0, cv0, oa, 0, 0, 0);
        ob = __builtin_amdgcn_mfma_f32_32x32x16_bf16(pa1, cv1, ob, 0, 0, 0);
    }

    oa = oa + ob;
    // full split-partial row-sum l_s for row i0+m (this lane's column)
    float l = (l01.x + l01.y) + (l23.x + l23.y);
    l += __shfl_xor(l, 32);
    const float rinv = __builtin_amdgcn_rcpf(l);

    // store normalized ratios r_s = O_s / l_s as bf16 (unit-scale, well-conditioned).
    // reg r -> row i_loc=(r&3)+8*(r>>2)+4h, col c=m ; l for row iloc lives in lane iloc
#pragma unroll
    for (int r = 0; r < 16; ++r) {
        int iloc = (r & 3) + 8 * (r >> 2) + 4 * h;
        float lr = __shfl(rinv, iloc);
        size_t row = (size_t)b * 8192 + i0 + iloc;
        Opart[((row << LSPLIT) | s) * 32 + m] = __float2bfloat16(oa[r] * lr);
    }
    if (h == 0)
        Lpart[(((size_t)b * 8192 + i0 + m) << LSPLIT) | s] = l;
}

// ---------------- Kernel C: weighted combine + epilogue ----------------
// out = (sum_s l_s * r_s) / (sum_s l_s) * gamma + in
__global__ __launch_bounds__(256) void combine_kernel(
    const unsigned short* __restrict__ Opart, const float* __restrict__ Lpart,
    const float* __restrict__ in, const float* __restrict__ gamma,
    float* __restrict__ out)
{
    const int gid = blockIdx.x * 256 + threadIdx.x;   // 0..262143
    const int row = gid >> 4;                          // 0..16383
    const int c2 = (gid & 15) * 2;
    const unsigned short* op = Opart + (((size_t)row << LSPLIT)) * 32 + c2;
    const float* lp = Lpart + ((size_t)row << LSPLIT);
    float4 l0 = *(const float4*)(lp);
    float4 l1 = *(const float4*)(lp + 4);
    float ls8[8] = {l0.x, l0.y, l0.z, l0.w, l1.x, l1.y, l1.z, l1.w};
    float ax = 0.f, ay = 0.f;
    float lsum = 0.f;
#pragma unroll
    for (int s = 0; s < (1 << LSPLIT); ++s) {
        ushort2 u = *(const ushort2*)(op + s * 32);
        float ls = ls8[s];
        ax += ls * __uint_as_float((unsigned)u.x << 16);
        ay += ls * __uint_as_float((unsigned)u.y << 16);
        lsum += ls;
    }
    const size_t base = (size_t)row * 32 + c2;
    float2 x = *(const float2*)(in + base);
    const float gl = gamma[0] / lsum;
    float2 r;
    r.x = ax * gl + x.x;
    r.y = ay * gl + x.y;
    *(float2*)(out + base) = r;
}

extern "C" void kernel_launch(void* const* d_in, const int* in_sizes, int n_in,
                              void* d_out, int out_size, void* d_ws, size_t ws_size,
                              hipStream_t stream) {
    const float* in = (const float*)d_in[0];
    const float* W1 = (const float*)d_in[1];
    const float* b1 = (const float*)d_in[2];
    const float* W2 = (const float*)d_in[3];
    const float* b2 = (const float*)d_in[4];
    const float* gamma = (const float*)d_in[5];
    float* out = (float*)d_out;

    __hip_bfloat16* Kq = (__hip_bfloat16*)d_ws;
    __hip_bfloat16* Vswz = Kq + KQ_ELEMS;
    __hip_bfloat16* Opart = (__hip_bfloat16*)((char*)d_ws + OPART_OFF);
    float* Lpart = (float*)(Opart + ((size_t)16384 << LSPLIT) * 32);

    proj_kernel<<<512, 512, 0, stream>>>(in, W1, b1, W2, b2, Kq, Vswz);
    flash_kernel<<<2 * 64 * (1 << LSPLIT), 256, 0, stream>>>(Kq, Vswz, Opart, Lpart);
    combine_kernel<<<1024, 256, 0, stream>>>((const unsigned short*)Opart, Lpart, in, gamma, out);
}

// Round 5
// 99.329 us; speedup vs baseline: 1.1116x; 1.0808x over previous
//
#include <hip/hip_runtime.h>
#include <hip/hip_bf16.h>
#include <math.h>

typedef __bf16 bf16x8 __attribute__((ext_vector_type(8)));
typedef __bf16 bf16x2 __attribute__((ext_vector_type(2)));
typedef short  s16x2  __attribute__((ext_vector_type(2)));
typedef short  s16x4  __attribute__((ext_vector_type(4)));
typedef float  floatx16 __attribute__((ext_vector_type(16)));
typedef unsigned u32x4 __attribute__((ext_vector_type(4)));

// Workspace layout (bytes):
//   Kq    bf16 [2][8192][16]        offset 0        (512 KB)  scaled by sqrt(log2 e)
//   Vswz  bf16 [2][8192][32]        offset 524288   (1 MB)    32x32x16 B-frag swizzled
//   Opart bf16 [2*8192][8][32]      offset 1572864  (8.4 MB)  normalized ratios r_s = O_s/l_s
//   Lpart f32  [2*8192][8]          after Opart     (512 KB)
#define KQ_ELEMS (2 * 8192 * 16)
#define OPART_OFF 1572864
#define SQRT_LOG2E 1.2011224087864498f
#define LSPLIT 3

// ---------------- Kernel A: projections ----------------
// Vswz layout = 32x32x16 B-fragment order (verified by R4 pass):
//   V[j][c] at flat = jt*1024 + g'*512 + hh*256 + c*8 + idx,
//   jl=j&31, g'=jl>>4, hh=(jl>>3)&1, idx=jl&7.
__global__ __launch_bounds__(512) void proj_kernel(
    const float* __restrict__ in, const float* __restrict__ W1,
    const float* __restrict__ b1, const float* __restrict__ W2,
    const float* __restrict__ b2,
    __hip_bfloat16* __restrict__ Kq, __hip_bfloat16* __restrict__ Vswz)
{
    __shared__ float Xs[32][32];
    __shared__ float W1s[16 * 32];
    __shared__ float W2s[32 * 32];
    const int t = threadIdx.x;
    const int bid = blockIdx.x;       // 0..511
    const int b = bid >> 8;
    const int hw = bid & 255;

    {
        int l = t >> 4, cs = (t & 15) * 2;
        float2 v = *(const float2*)(in + (((size_t)b * 32 + l) * 256 + hw) * 32 + cs);
        *(float2*)&Xs[l][cs] = v;
    }
    if (t < 128) *(float4*)&W1s[t * 4] = *(const float4*)(W1 + t * 4);
    if (t < 256) *(float4*)&W2s[t * 4] = *(const float4*)(W2 + t * 4);
    __syncthreads();

    const int c = t & 31;
    const int g = t >> 5;             // 0..15

    {
        int o = g;                    // 0..15
        float a0 = b1[o], a1 = 0.f;
#pragma unroll
        for (int l = 0; l < 16; ++l) {
            a0 += W1s[o * 32 + l] * Xs[l][c];
            a1 += W1s[o * 32 + 16 + l] * Xs[16 + l][c];
        }
        float acc = a0 + a1;
        int k = c >> 1;
        int i = (c & 1) * 4096 + o * 256 + hw;
        Kq[((size_t)b * 8192 + i) * 16 + k] = __float2bfloat16(acc * SQRT_LOG2E);
    }
#pragma unroll
    for (int oo = 0; oo < 2; ++oo) {
        int o = g * 2 + oo;           // 0..31
        float a0 = b2[o], a1 = 0.f;
#pragma unroll
        for (int l = 0; l < 16; ++l) {
            a0 += W2s[o * 32 + l] * Xs[l][c];
            a1 += W2s[o * 32 + 16 + l] * Xs[16 + l][c];
        }
        float acc = a0 + a1;
        // position j = o*256 + hw, channel c; x16 B-frag swizzle:
        int jt = o * 8 + (hw >> 5);
        int gp = (hw >> 4) & 1, hh = (hw >> 3) & 1, idx = hw & 7;
        Vswz[(size_t)b * 262144 + jt * 1024 + gp * 512 + hh * 256 + c * 8 + idx] =
            __float2bfloat16(acc);
    }
}

// ---------------- Kernel B: flash attention, LDS-free, bf16 normalized partials ----------------
// block = 256 thr (4 waves), each wave owns 32 i-rows. grid = 2 * 64 * 8 = 1024.
// v6 (post-mortem of v3-v5): flash pinned at ~41us across ALL inner-loop variants.
// R2 PMC: Occupancy 27.7% = ~2 waves/SIMD despite grid providing 4 -> REGISTER-limited
// (VGPR 52 + AGPR accumulators ~128 total alloc). The serial chain
// (load->S-MFMA->exp2->pack->shfl->PV) can't hide under 2 waves. v6 = register economy:
//   - hard cap __launch_bounds__(256,4)  (reg budget 128, 4 waves/SIMD; R1's best
//     total 101.7 was the only capped variant)
//   - ONE accumulator oa (both PV MFMAs chain into it; acc-forwarding handles it)
//   - per-half-tile transients (2 g-groups live at once, not e[16]/cp[8]/pa[8])
//   - native 32x32x16 PV MFMAs, verified P-regroup via shfl_xor(.,32)+select
// NOTE: partials via plain streaming stores, NOT atomics (atomic RMW pinned ~44us).
__global__ __launch_bounds__(256, 4) void flash_kernel(
    const __hip_bfloat16* __restrict__ Kq, const __hip_bfloat16* __restrict__ Vswz,
    __hip_bfloat16* __restrict__ Opart, float* __restrict__ Lpart)
{
    const int t = threadIdx.x;
    const int lane = t & 63;
    const int wv = t >> 6;            // 0..3
    const int m = lane & 31;
    const int h = lane >> 5;          // 0/1
    const bool hi = (h != 0);

    const int bid = blockIdx.x;
    const int s = bid & ((1 << LSPLIT) - 1);
    const int itile = (bid >> LSPLIT) & 63;
    const int b = bid >> (LSPLIT + 6);
    const int i0 = itile * 128 + wv * 32;
    const int niter = (8192 >> LSPLIT) >> 5;   // 32 tiles of 32 j
    const int jt0 = s * niter;

    const __hip_bfloat16* Kb = Kq + (size_t)b * 8192 * 16;
    const __hip_bfloat16* Vb = Vswz + (size_t)b * 262144 + h * 256 + m * 8;

    // Q B-frag (regs): B[k=8h+idx][n=m] = Kq[i0+m][8h+idx]
    const bf16x8 bq = *(const bf16x8*)(Kb + (size_t)(i0 + m) * 16 + h * 8);

    floatx16 oa = {};
    float l0 = 0.f, l1 = 0.f, l2 = 0.f, l3 = 0.f;

    // ---- software pipeline: preload tile jt0 ----
    bf16x8 ak = *(const bf16x8*)(Kb + (size_t)(jt0 * 32 + m) * 16 + h * 8);
    bf16x8 vb0 = *(const bf16x8*)(Vb + (size_t)jt0 * 1024 + 0);
    bf16x8 vb1 = *(const bf16x8*)(Vb + (size_t)jt0 * 1024 + 512);

#pragma unroll 2
    for (int it = 0; it < niter; ++it) {
        const bf16x8 cak = ak;
        const bf16x8 cv0 = vb0, cv1 = vb1;
        if (it + 1 < niter) {
            const int jn = jt0 + it + 1;
            ak  = *(const bf16x8*)(Kb + (size_t)(jn * 32 + m) * 16 + h * 8);
            vb0 = *(const bf16x8*)(Vb + (size_t)jn * 1024 + 0);
            vb1 = *(const bf16x8*)(Vb + (size_t)jn * 1024 + 512);
        }

        // S^T(32j x 32i) = K(A) x Q(B), K=16 exact
        floatx16 sc = __builtin_amdgcn_mfma_f32_32x32x16_bf16(cak, bq, (floatx16){}, 0, 0, 0);

        // P = 2^S ; sc reg 4g+idx holds j_loc = 8g+4h+idx, i = m.
        // Process one 16-j half-tile at a time (g pair) -> small transient live set.
#pragma unroll
        for (int half = 0; half < 2; ++half) {
            unsigned c0a, c0b, c1a, c1b;
            {
                const int g = half * 2;
                float e0 = __builtin_amdgcn_exp2f(sc[4 * g + 0]);
                float e1 = __builtin_amdgcn_exp2f(sc[4 * g + 1]);
                float e2 = __builtin_amdgcn_exp2f(sc[4 * g + 2]);
                float e3 = __builtin_amdgcn_exp2f(sc[4 * g + 3]);
                l0 += e0; l1 += e1; l2 += e2; l3 += e3;
#if defined(__has_builtin) && __has_builtin(__builtin_amdgcn_cvt_pk_bf16_f32)
                bf16x2 pk0 = __builtin_amdgcn_cvt_pk_bf16_f32(e0, e1);
                bf16x2 pk1 = __builtin_amdgcn_cvt_pk_bf16_f32(e2, e3);
#else
                bf16x2 pk0 = {(__bf16)e0, (__bf16)e1};
                bf16x2 pk1 = {(__bf16)e2, (__bf16)e3};
#endif
                c0a = __builtin_bit_cast(unsigned, pk0);
                c0b = __builtin_bit_cast(unsigned, pk1);
            }
            {
                const int g = half * 2 + 1;
                float e0 = __builtin_amdgcn_exp2f(sc[4 * g + 0]);
                float e1 = __builtin_amdgcn_exp2f(sc[4 * g + 1]);
                float e2 = __builtin_amdgcn_exp2f(sc[4 * g + 2]);
                float e3 = __builtin_amdgcn_exp2f(sc[4 * g + 3]);
                l0 += e0; l1 += e1; l2 += e2; l3 += e3;
#if defined(__has_builtin) && __has_builtin(__builtin_amdgcn_cvt_pk_bf16_f32)
                bf16x2 pk0 = __builtin_amdgcn_cvt_pk_bf16_f32(e0, e1);
                bf16x2 pk1 = __builtin_amdgcn_cvt_pk_bf16_f32(e2, e3);
#else
                bf16x2 pk0 = {(__bf16)e0, (__bf16)e1};
                bf16x2 pk1 = {(__bf16)e2, (__bf16)e3};
#endif
                c1a = __builtin_bit_cast(unsigned, pk0);
                c1b = __builtin_bit_cast(unsigned, pk1);
            }
            // Regroup to x16 A-layout (verified in R4): lane (m,h) elem idx holds
            // P[i=m][j = 16*half + 8h + idx].
            unsigned x0a = __shfl_xor((int)c0a, 32), x0b = __shfl_xor((int)c0b, 32);
            unsigned x1a = __shfl_xor((int)c1a, 32), x1b = __shfl_xor((int)c1b, 32);
            u32x4 pau = { hi ? x1a : c0a, hi ? x1b : c0b,
                          hi ? c1a : x0a, hi ? c1b : x0b };
            bf16x8 pa = __builtin_bit_cast(bf16x8, pau);
            oa = __builtin_amdgcn_mfma_f32_32x32x16_bf16(pa, half ? cv1 : cv0, oa, 0, 0, 0);
        }
    }

    // full split-partial row-sum l_s for row i0+m (this lane's column)
    float l = (l0 + l1) + (l2 + l3);
    l += __shfl_xor(l, 32);
    const float rinv = __builtin_amdgcn_rcpf(l);

    // store normalized ratios r_s = O_s / l_s as bf16 (unit-scale, well-conditioned).
    // reg r -> row i_loc=(r&3)+8*(r>>2)+4h, col c=m ; l for row iloc lives in lane iloc
#pragma unroll
    for (int r = 0; r < 16; ++r) {
        int iloc = (r & 3) + 8 * (r >> 2) + 4 * h;
        float lr = __shfl(rinv, iloc);
        size_t row = (size_t)b * 8192 + i0 + iloc;
        Opart[((row << LSPLIT) | s) * 32 + m] = __float2bfloat16(oa[r] * lr);
    }
    if (h == 0)
        Lpart[(((size_t)b * 8192 + i0 + m) << LSPLIT) | s] = l;
}

// ---------------- Kernel C: weighted combine + epilogue ----------------
// out = (sum_s l_s * r_s) / (sum_s l_s) * gamma + in
__global__ __launch_bounds__(256) void combine_kernel(
    const unsigned short* __restrict__ Opart, const float* __restrict__ Lpart,
    const float* __restrict__ in, const float* __restrict__ gamma,
    float* __restrict__ out)
{
    const int gid = blockIdx.x * 256 + threadIdx.x;   // 0..262143
    const int row = gid >> 4;                          // 0..16383
    const int c2 = (gid & 15) * 2;
    const unsigned short* op = Opart + (((size_t)row << LSPLIT)) * 32 + c2;
    const float* lp = Lpart + ((size_t)row << LSPLIT);
    float4 l0 = *(const float4*)(lp);
    float4 l1 = *(const float4*)(lp + 4);
    float ls8[8] = {l0.x, l0.y, l0.z, l0.w, l1.x, l1.y, l1.z, l1.w};
    float ax = 0.f, ay = 0.f;
    float lsum = 0.f;
#pragma unroll
    for (int s = 0; s < (1 << LSPLIT); ++s) {
        ushort2 u = *(const ushort2*)(op + s * 32);
        float ls = ls8[s];
        ax += ls * __uint_as_float((unsigned)u.x << 16);
        ay += ls * __uint_as_float((unsigned)u.y << 16);
        lsum += ls;
    }
    const size_t base = (size_t)row * 32 + c2;
    float2 x = *(const float2*)(in + base);
    const float gl = gamma[0] / lsum;
    float2 r;
    r.x = ax * gl + x.x;
    r.y = ay * gl + x.y;
    *(float2*)(out + base) = r;
}

extern "C" void kernel_launch(void* const* d_in, const int* in_sizes, int n_in,
                              void* d_out, int out_size, void* d_ws, size_t ws_size,
                              hipStream_t stream) {
    const float* in = (const float*)d_in[0];
    const float* W1 = (const float*)d_in[1];
    const float* b1 = (const float*)d_in[2];
    const float* W2 = (const float*)d_in[3];
    const float* b2 = (const float*)d_in[4];
    const float* gamma = (const float*)d_in[5];
    float* out = (float*)d_out;

    __hip_bfloat16* Kq = (__hip_bfloat16*)d_ws;
    __hip_bfloat16* Vswz = Kq + KQ_ELEMS;
    __hip_bfloat16* Opart = (__hip_bfloat16*)((char*)d_ws + OPART_OFF);
    float* Lpart = (float*)(Opart + ((size_t)16384 << LSPLIT) * 32);

    proj_kernel<<<512, 512, 0, stream>>>(in, W1, b1, W2, b2, Kq, Vswz);
    flash_kernel<<<2 * 64 * (1 << LSPLIT), 256, 0, stream>>>(Kq, Vswz, Opart, Lpart);
    combine_kernel<<<1024, 256, 0, stream>>>((const unsigned short*)Opart, Lpart, in, gamma, out);
}

// Round 6
// 95.325 us; speedup vs baseline: 1.1583x; 1.0420x over previous
//
#include <hip/hip_runtime.h>
#include <hip/hip_bf16.h>
#include <math.h>

typedef __bf16 bf16x8 __attribute__((ext_vector_type(8)));
typedef __bf16 bf16x2 __attribute__((ext_vector_type(2)));
typedef float  floatx16 __attribute__((ext_vector_type(16)));
typedef unsigned u32x4 __attribute__((ext_vector_type(4)));

// Workspace layout (bytes):
//   Kq    bf16 [2][8192][16]        offset 0        (512 KB)  scaled by sqrt(log2 e)
//   Vswz  bf16 [2][8192][32]        offset 524288   (1 MB)    P-natural-order B-frag swizzle
//   Opart bf16 [2*8192][8][32]      offset 1572864  (8.4 MB)  normalized ratios r_s = O_s/l_s
//   Lpart f32  [2*8192][8]          after Opart     (512 KB)
#define KQ_ELEMS (2 * 8192 * 16)
#define OPART_OFF 1572864
#define SQRT_LOG2E 1.2011224087864498f
#define LSPLIT 3

// ---------------- Kernel A: projections ----------------
// v7 Vswz layout: B-fragment in P's NATURAL slot order, so flash needs ZERO
// cross-lane ops. Slot map per 32-j tile (frag f = jl>>4, jj = jl&15):
//   owner half  h = (jj>>2)&1
//   elem index  idx = (jj&3) | (((jj>>3)&1)<<2)
//   flat = jt*1024 + f*512 + h*256 + c*8 + idx
// This makes A-slot s and B-slot s refer to the same j by construction:
// P natural layout gives lane h the pairs j = 16f + 4h + {0,1,2,3, 8,9,10,11}.
__global__ __launch_bounds__(512) void proj_kernel(
    const float* __restrict__ in, const float* __restrict__ W1,
    const float* __restrict__ b1, const float* __restrict__ W2,
    const float* __restrict__ b2,
    __hip_bfloat16* __restrict__ Kq, __hip_bfloat16* __restrict__ Vswz)
{
    __shared__ float Xs[32][32];
    __shared__ float W1s[16 * 32];
    __shared__ float W2s[32 * 32];
    const int t = threadIdx.x;
    const int bid = blockIdx.x;       // 0..511
    const int b = bid >> 8;
    const int hw = bid & 255;

    {
        int l = t >> 4, cs = (t & 15) * 2;
        float2 v = *(const float2*)(in + (((size_t)b * 32 + l) * 256 + hw) * 32 + cs);
        *(float2*)&Xs[l][cs] = v;
    }
    if (t < 128) *(float4*)&W1s[t * 4] = *(const float4*)(W1 + t * 4);
    if (t < 256) *(float4*)&W2s[t * 4] = *(const float4*)(W2 + t * 4);
    __syncthreads();

    const int c = t & 31;
    const int g = t >> 5;             // 0..15

    {
        int o = g;                    // 0..15
        float a0 = b1[o], a1 = 0.f;
#pragma unroll
        for (int l = 0; l < 16; ++l) {
            a0 += W1s[o * 32 + l] * Xs[l][c];
            a1 += W1s[o * 32 + 16 + l] * Xs[16 + l][c];
        }
        float acc = a0 + a1;
        int k = c >> 1;
        int i = (c & 1) * 4096 + o * 256 + hw;
        Kq[((size_t)b * 8192 + i) * 16 + k] = __float2bfloat16(acc * SQRT_LOG2E);
    }
#pragma unroll
    for (int oo = 0; oo < 2; ++oo) {
        int o = g * 2 + oo;           // 0..31
        float a0 = b2[o], a1 = 0.f;
#pragma unroll
        for (int l = 0; l < 16; ++l) {
            a0 += W2s[o * 32 + l] * Xs[l][c];
            a1 += W2s[o * 32 + 16 + l] * Xs[16 + l][c];
        }
        float acc = a0 + a1;
        // position j = o*256 + hw, channel c; P-natural-order swizzle (v7):
        int jt = o * 8 + (hw >> 5);          // j >> 5
        int f  = (hw >> 4) & 1;              // frag: jl 0..15 -> 0, 16..31 -> 1
        int hh = (hw >> 2) & 1;              // owner half
        int idx = (hw & 3) | (((hw >> 3) & 1) << 2);
        Vswz[(size_t)b * 262144 + jt * 1024 + f * 512 + hh * 256 + c * 8 + idx] =
            __float2bfloat16(acc);
    }
}

// ---------------- Kernel B: flash attention, LDS-free, bf16 normalized partials ----------------
// block = 256 thr (4 waves), each wave owns 32 i-rows. grid = 2 * 64 * 8 = 1024.
// v7 (post-mortem of v6): register economy confirmed (flash ~41 -> ~33us), but still
// ~3x above pipe floor. Remaining critical-path segment: the P-regroup
// (8 shfl_xor on the DS pipe + 8 selects per iter, with lgkmcnt stalls between
// exp2 and PV-MFMA). v7 deletes it: V is pre-swizzled (in proj) into P's NATURAL
// slot order, so the cvt_pk outputs ARE the x16 A-fragment dwords:
//   pa0 = {cp00,cp01,cp10,cp11}, pa1 = {cp20,cp21,cp30,cp31}.   Zero cross-lane ops.
// Keeps: __launch_bounds__(256,4) reg cap, single accumulator, native x16 MFMAs,
// depth-1 prefetch, streaming stores (NOT atomics: RMW pinned ~44us).
__global__ __launch_bounds__(256, 4) void flash_kernel(
    const __hip_bfloat16* __restrict__ Kq, const __hip_bfloat16* __restrict__ Vswz,
    __hip_bfloat16* __restrict__ Opart, float* __restrict__ Lpart)
{
    const int t = threadIdx.x;
    const int lane = t & 63;
    const int wv = t >> 6;            // 0..3
    const int m = lane & 31;
    const int h = lane >> 5;          // 0/1

    const int bid = blockIdx.x;
    const int s = bid & ((1 << LSPLIT) - 1);
    const int itile = (bid >> LSPLIT) & 63;
    const int b = bid >> (LSPLIT + 6);
    const int i0 = itile * 128 + wv * 32;
    const int niter = (8192 >> LSPLIT) >> 5;   // 32 tiles of 32 j
    const int jt0 = s * niter;

    const __hip_bfloat16* Kb = Kq + (size_t)b * 8192 * 16;
    const __hip_bfloat16* Vb = Vswz + (size_t)b * 262144 + h * 256 + m * 8;

    // Q B-frag (regs): B[k=8h+idx][n=m] = Kq[i0+m][8h+idx]
    const bf16x8 bq = *(const bf16x8*)(Kb + (size_t)(i0 + m) * 16 + h * 8);

    floatx16 oa = {};
    float l0 = 0.f, l1 = 0.f, l2 = 0.f, l3 = 0.f;

    // ---- software pipeline: preload tile jt0 ----
    bf16x8 ak = *(const bf16x8*)(Kb + (size_t)(jt0 * 32 + m) * 16 + h * 8);
    bf16x8 vb0 = *(const bf16x8*)(Vb + (size_t)jt0 * 1024 + 0);
    bf16x8 vb1 = *(const bf16x8*)(Vb + (size_t)jt0 * 1024 + 512);

#pragma unroll 2
    for (int it = 0; it < niter; ++it) {
        const bf16x8 cak = ak;
        const bf16x8 cv0 = vb0, cv1 = vb1;
        if (it + 1 < niter) {
            const int jn = jt0 + it + 1;
            ak  = *(const bf16x8*)(Kb + (size_t)(jn * 32 + m) * 16 + h * 8);
            vb0 = *(const bf16x8*)(Vb + (size_t)jn * 1024 + 0);
            vb1 = *(const bf16x8*)(Vb + (size_t)jn * 1024 + 512);
        }

        // S^T(32j x 32i) = K(A) x Q(B), K=16 exact
        floatx16 sc = __builtin_amdgcn_mfma_f32_32x32x16_bf16(cak, bq, (floatx16){}, 0, 0, 0);

        // P = 2^S ; sc reg 4g+idx holds j_loc = 8g+4h+idx, i = m.
        // cvt_pk pairs ARE the A-frag dwords under the v7 V-swizzle.
#pragma unroll
        for (int half = 0; half < 2; ++half) {
            u32x4 pau;
#pragma unroll
            for (int gg = 0; gg < 2; ++gg) {
                const int g = half * 2 + gg;
                float e0 = __builtin_amdgcn_exp2f(sc[4 * g + 0]);
                float e1 = __builtin_amdgcn_exp2f(sc[4 * g + 1]);
                float e2 = __builtin_amdgcn_exp2f(sc[4 * g + 2]);
                float e3 = __builtin_amdgcn_exp2f(sc[4 * g + 3]);
                l0 += e0; l1 += e1; l2 += e2; l3 += e3;
#if defined(__has_builtin) && __has_builtin(__builtin_amdgcn_cvt_pk_bf16_f32)
                bf16x2 pk0 = __builtin_amdgcn_cvt_pk_bf16_f32(e0, e1);
                bf16x2 pk1 = __builtin_amdgcn_cvt_pk_bf16_f32(e2, e3);
#else
                bf16x2 pk0 = {(__bf16)e0, (__bf16)e1};
                bf16x2 pk1 = {(__bf16)e2, (__bf16)e3};
#endif
                pau[gg * 2 + 0] = __builtin_bit_cast(unsigned, pk0);
                pau[gg * 2 + 1] = __builtin_bit_cast(unsigned, pk1);
            }
            bf16x8 pa = __builtin_bit_cast(bf16x8, pau);
            oa = __builtin_amdgcn_mfma_f32_32x32x16_bf16(pa, half ? cv1 : cv0, oa, 0, 0, 0);
        }
    }

    // full split-partial row-sum l_s for row i0+m (this lane's column)
    float l = (l0 + l1) + (l2 + l3);
    l += __shfl_xor(l, 32);
    const float rinv = __builtin_amdgcn_rcpf(l);

    // store normalized ratios r_s = O_s / l_s as bf16 (unit-scale, well-conditioned).
    // reg r -> row i_loc=(r&3)+8*(r>>2)+4h, col c=m ; l for row iloc lives in lane iloc
#pragma unroll
    for (int r = 0; r < 16; ++r) {
        int iloc = (r & 3) + 8 * (r >> 2) + 4 * h;
        float lr = __shfl(rinv, iloc);
        size_t row = (size_t)b * 8192 + i0 + iloc;
        Opart[((row << LSPLIT) | s) * 32 + m] = __float2bfloat16(oa[r] * lr);
    }
    if (h == 0)
        Lpart[(((size_t)b * 8192 + i0 + m) << LSPLIT) | s] = l;
}

// ---------------- Kernel C: weighted combine + epilogue ----------------
// out = (sum_s l_s * r_s) / (sum_s l_s) * gamma + in
__global__ __launch_bounds__(256) void combine_kernel(
    const unsigned short* __restrict__ Opart, const float* __restrict__ Lpart,
    const float* __restrict__ in, const float* __restrict__ gamma,
    float* __restrict__ out)
{
    const int gid = blockIdx.x * 256 + threadIdx.x;   // 0..262143
    const int row = gid >> 4;                          // 0..16383
    const int c2 = (gid & 15) * 2;
    const unsigned short* op = Opart + (((size_t)row << LSPLIT)) * 32 + c2;
    const float* lp = Lpart + ((size_t)row << LSPLIT);
    float4 l0 = *(const float4*)(lp);
    float4 l1 = *(const float4*)(lp + 4);
    float ls8[8] = {l0.x, l0.y, l0.z, l0.w, l1.x, l1.y, l1.z, l1.w};
    float ax = 0.f, ay = 0.f;
    float lsum = 0.f;
#pragma unroll
    for (int s = 0; s < (1 << LSPLIT); ++s) {
        ushort2 u = *(const ushort2*)(op + s * 32);
        float ls = ls8[s];
        ax += ls * __uint_as_float((unsigned)u.x << 16);
        ay += ls * __uint_as_float((unsigned)u.y << 16);
        lsum += ls;
    }
    const size_t base = (size_t)row * 32 + c2;
    float2 x = *(const float2*)(in + base);
    const float gl = gamma[0] / lsum;
    float2 r;
    r.x = ax * gl + x.x;
    r.y = ay * gl + x.y;
    *(float2*)(out + base) = r;
}

extern "C" void kernel_launch(void* const* d_in, const int* in_sizes, int n_in,
                              void* d_out, int out_size, void* d_ws, size_t ws_size,
                              hipStream_t stream) {
    const float* in = (const float*)d_in[0];
    const float* W1 = (const float*)d_in[1];
    const float* b1 = (const float*)d_in[2];
    const float* W2 = (const float*)d_in[3];
    const float* b2 = (const float*)d_in[4];
    const float* gamma = (const float*)d_in[5];
    float* out = (float*)d_out;

    __hip_bfloat16* Kq = (__hip_bfloat16*)d_ws;
    __hip_bfloat16* Vswz = Kq + KQ_ELEMS;
    __hip_bfloat16* Opart = (__hip_bfloat16*)((char*)d_ws + OPART_OFF);
    float* Lpart = (float*)(Opart + ((size_t)16384 << LSPLIT) * 32);

    proj_kernel<<<512, 512, 0, stream>>>(in, W1, b1, W2, b2, Kq, Vswz);
    flash_kernel<<<2 * 64 * (1 << LSPLIT), 256, 0, stream>>>(Kq, Vswz, Opart, Lpart);
    combine_kernel<<<1024, 256, 0, stream>>>((const unsigned short*)Opart, Lpart, in, gamma, out);
}